// Round 12
// baseline (1011.399 us; speedup 1.0000x reference)
//
#include <hip/hip_runtime.h>
#include <hip/hip_bf16.h>
#include <math.h>

#define NSMP 32768
#define NFR 128
#define NCH 1024
#define NB 4

typedef __attribute__((ext_vector_type(8))) short short8;
typedef __attribute__((ext_vector_type(4))) float f32x4;
typedef unsigned short ushort;

__device__ __forceinline__ void split_bf(float v, ushort& h, ushort& l) {
  __hip_bfloat16 bh = __float2bfloat16(v);
  float r = v - __bfloat162float(bh);
  __hip_bfloat16 bl = __float2bfloat16(r);
  h = *reinterpret_cast<ushort*>(&bh);
  l = *reinterpret_cast<ushort*>(&bl);
}

__device__ __forceinline__ void gload_lds16(const ushort* g, ushort* l) {
  __builtin_amdgcn_global_load_lds((const __attribute__((address_space(1))) void*)g,
                                   (__attribute__((address_space(3))) void*)l, 16, 0, 0);
}

// device-scope barrier for 256 co-resident blocks (1/CU guaranteed by 96KB LDS + launch_bounds)
__device__ __forceinline__ void gsync(unsigned* cnt, unsigned target) {
  __syncthreads();
  if (threadIdx.x == 0) {
    __threadfence();                 // release: flush this XCD's L2 so peers see yp/hT/h writes
    atomicAdd(cnt, 1u);
    while (atomicAdd(cnt, 0u) < target) __builtin_amdgcn_s_sleep(2);
    __threadfence();                 // acquire: invalidate L1/L2 so we see peers' writes
  }
  __syncthreads();
}

// ---------------- STFT: emits h (f32) + transposed hi/lo bf16 hT[t][c]; zeros hT pad rows ----------------
__global__ __launch_bounds__(256) void stft_kernel(const float* __restrict__ x,
                                                   float* __restrict__ h,
                                                   ushort* __restrict__ hTh,
                                                   ushort* __restrict__ hTl,
                                                   ushort* __restrict__ hTh1,
                                                   ushort* __restrict__ hTl1) {
  __shared__ float re[2048];
  __shared__ float im[2048];
  __shared__ float twr[1024];
  __shared__ float twi[1024];
  int bid = blockIdx.x;
  int b = bid >> 7;
  int f = bid & 127;
  int tid = threadIdx.x;
  const float TWO_PI = 6.28318530717958647692f;
  if (f < 64) {
    size_t pidx = ((size_t)b * 192 + 128 + f) * 1024 + tid * 4;
    uint2 z = {0u, 0u};
    *(uint2*)&hTh[pidx] = z;  *(uint2*)&hTl[pidx] = z;
    *(uint2*)&hTh1[pidx] = z; *(uint2*)&hTl1[pidx] = z;
  }
  for (int k = tid; k < 1024; k += 256) {
    float ang = -TWO_PI * (float)k / 2048.0f;
    float sn, cs;
    sincosf(ang, &sn, &cs);
    twr[k] = cs; twi[k] = sn;
  }
  for (int i = tid; i < 2048; i += 256) {
    int rev = (int)(__brev((unsigned)i) >> 21);
    int pos = f * 256 + rev;
    float v = (pos < NSMP) ? x[b * NSMP + pos] : 0.f;
    float w = 0.5f - 0.5f * cosf(TWO_PI * (float)rev / 2047.0f);  // jnp.hanning(2048)
    re[i] = v * w;
    im[i] = 0.f;
  }
  __syncthreads();
  for (int s = 0; s < 11; ++s) {
    for (int q = 0; q < 4; ++q) {
      int bi = tid + q * 256;
      int half = 1 << s;
      int j = bi & (half - 1);
      int i0 = ((bi >> s) << (s + 1)) | j;
      int i1 = i0 + half;
      int ti = j << (10 - s);
      float cs = twr[ti], sn = twi[ti];
      float ur = re[i0], ui = im[i0];
      float vr = re[i1], vi = im[i1];
      float tr = vr * cs - vi * sn;
      float tti = vr * sn + vi * cs;
      re[i0] = ur + tr; im[i0] = ui + tti;
      re[i1] = ur - tr; im[i1] = ui - tti;
    }
    __syncthreads();
  }
  for (int k = tid; k < 1024; k += 256) {
    float m = sqrtf(re[k] * re[k] + im[k] * im[k]);
    h[(b * NCH + k) * NFR + f] = m;
    ushort hi, lo;
    split_bf(m, hi, lo);
    size_t tidx = ((size_t)b * 192 + f) * 1024 + k;
    hTh[tidx] = hi;
    hTl[tidx] = lo;
  }
}

// ---------------- split encw into per-tap hi/lo bf16 weight arrays ----------------
__global__ __launch_bounds__(256) void wsplit_kernel(const float* __restrict__ encw,
                                                     ushort* __restrict__ w0h, ushort* __restrict__ w0l,
                                                     ushort* __restrict__ w1h, ushort* __restrict__ w1l) {
  size_t F = (size_t)blockIdx.x * 256 + threadIdx.x;  // 4,194,304 float4s
  float4 v = ((const float4*)encw)[F];
  size_t lo_idx = F >> 9;            // l*1024+o
  int c0 = (int)(F & 511) * 2;
  size_t base = lo_idx * 1024 + c0;
  ushort h0, l0, h1, l1;
  split_bf(v.x, h0, l0);
  split_bf(v.z, h1, l1);
  *(ushort2*)&w0h[base] = (ushort2){h0, h1};
  *(ushort2*)&w0l[base] = (ushort2){l0, l1};
  split_bf(v.y, h0, l0);
  split_bf(v.w, h1, l1);
  *(ushort2*)&w1h[base] = (ushort2){h0, h1};
  *(ushort2*)&w1l[base] = (ushort2){l0, l1};
}

// ---------------- fused conv stack: 8 x {split-K MFMA -> gsync -> epilogue -> gsync} ----------------
// 256 blocks (1/CU co-resident), block = (og 0..7, b 0..3, s 0..7). Bodies identical to round 9/10.
__global__ __launch_bounds__(256, 1) void conv_stack(
    const ushort* __restrict__ w0hB, const ushort* __restrict__ w0lB,
    const ushort* __restrict__ w1hB, const ushort* __restrict__ w1lB,
    const float* __restrict__ encb,
    float* __restrict__ h0, float* __restrict__ h1,
    ushort* __restrict__ hTh0, ushort* __restrict__ hTl0,
    ushort* __restrict__ hTh1, ushort* __restrict__ hTl1,
    float* __restrict__ yp, float* __restrict__ zbuf,
    unsigned* __restrict__ cnt) {
  __shared__ ushort lds[49152];  // mfma: 3 x 16384; epi reuses front as float T[16][132]
  int tid = threadIdx.x;
  int bid = blockIdx.x;
  int og8 = bid >> 5;          // 0..7
  int b = (bid >> 3) & 3;      // 0..3
  int s = bid & 7;             // 0..7
  int og = og8 * 128;
  int wid = tid >> 6, lane = tid & 63;
  int wr = (wid >> 1) * 64, wc = (wid & 1) * 64;
  int lr = lane & 15, lk = lane >> 4;
  int srow = lane >> 2;
  int sgr = ((lane & 3) ^ ((lane >> 3) & 3)) * 8;

  const int dil[8] = {1, 2, 4, 8, 16, 32, 64, 1};
  float* bufs[2] = {h0, h1};
  ushort* thh[2] = {hTh0, hTh1};
  ushort* thl[2] = {hTl0, hTl1};
  unsigned target = 0;

  for (int l = 0; l < 8; ++l) {
    int D = dil[l];
    const ushort* w0h = w0hB + (size_t)l * 1048576;
    const ushort* w0l = w0lB + (size_t)l * 1048576;
    const ushort* w1h = w1hB + (size_t)l * 1048576;
    const ushort* w1l = w1lB + (size_t)l * 1048576;
    int pi = l & 1, po = (l + 1) & 1;
    const ushort* hb_h = thh[pi] + (size_t)b * 192 * 1024;
    const ushort* hb_l = thl[pi] + (size_t)b * 192 * 1024;

    // ======== MFMA stage (identical body to round 9/10) ========
    f32x4 acc[4][4];
#pragma unroll
    for (int m = 0; m < 4; ++m)
#pragma unroll
      for (int n = 0; n < 4; ++n) acc[m][n] = (f32x4){0.f, 0.f, 0.f, 0.f};

    auto stage = [&](int buf, int p) {
      const ushort* Wh = (p < 4) ? w0h : w1h;
      const ushort* Wl = (p < 4) ? w0l : w1l;
      int rowoff = (p < 4) ? 0 : D;
      int c0 = s * 128 + (p & 3) * 32 + sgr;
      ushort* dbase = &lds[buf * 16384 + wid * 4096];
#pragma unroll
      for (int j = 0; j < 8; ++j) {
        int row = j * 16 + srow;
        const ushort* src;
        if (wid == 0)      src = Wh   + (size_t)(og + row) * 1024 + c0;
        else if (wid == 1) src = Wl   + (size_t)(og + row) * 1024 + c0;
        else if (wid == 2) src = hb_h + (size_t)(rowoff + row) * 1024 + c0;
        else               src = hb_l + (size_t)(rowoff + row) * 1024 + c0;
        gload_lds16(src, dbase + j * 512);
      }
    };

    auto compute = [&](int buf) {
      const ushort* base = &lds[buf * 16384];
      short8 ah[4], al[4], bh[4], bl[4];
#pragma unroll
      for (int m = 0; m < 4; ++m) {
        int ar = wr + m * 16 + lr;
        int off = ar * 32 + ((lk ^ ((ar >> 1) & 3)) << 3);
        ah[m] = *(const short8*)&base[off];
        al[m] = *(const short8*)&base[4096 + off];
      }
#pragma unroll
      for (int n = 0; n < 4; ++n) {
        int br = wc + n * 16 + lr;
        int off = br * 32 + ((lk ^ ((br >> 1) & 3)) << 3);
        bh[n] = *(const short8*)&base[8192 + off];
        bl[n] = *(const short8*)&base[12288 + off];
      }
#pragma unroll
      for (int m = 0; m < 4; ++m)
#pragma unroll
        for (int n = 0; n < 4; ++n) {
          acc[m][n] = __builtin_amdgcn_mfma_f32_16x16x32_bf16(ah[m], bh[n], acc[m][n], 0, 0, 0);
          acc[m][n] = __builtin_amdgcn_mfma_f32_16x16x32_bf16(ah[m], bl[n], acc[m][n], 0, 0, 0);
          acc[m][n] = __builtin_amdgcn_mfma_f32_16x16x32_bf16(al[m], bh[n], acc[m][n], 0, 0, 0);
        }
    };

    stage(0, 0);
    stage(1, 1);
#pragma unroll
    for (int p = 0; p < 8; ++p) {
      if (p < 7) asm volatile("s_waitcnt vmcnt(8)" ::: "memory");
      else       asm volatile("s_waitcnt vmcnt(0)" ::: "memory");
      __builtin_amdgcn_s_barrier();
      if (p + 2 < 8) stage((p + 2) % 3, p + 2);
      compute(p % 3);
    }

    {
      float* dst = yp + (size_t)(s * 4 + b) * 131072;
#pragma unroll
      for (int m = 0; m < 4; ++m)
#pragma unroll
        for (int n = 0; n < 4; ++n)
#pragma unroll
          for (int r = 0; r < 4; ++r) {
            int orow = og + wr + m * 16 + lk * 4 + r;
            int col = wc + n * 16 + lr;
            dst[orow * 128 + col] = acc[m][n][r];
          }
    }

    target += 256;
    gsync(cnt, target);

    // ======== Epilogue stage: rows [og + s*16, og + s*16 + 16), batch b ========
    {
      float* T = (float*)lds;  // [16][132]
      const float* hin = bufs[pi];
      float* hout = bufs[po];
      ushort* eTh = thh[po];
      ushort* eTl = thl[po];
      int oge = og + s * 16;
#pragma unroll
      for (int j = 0; j < 8; ++j) {
        int flat = j * 256 + tid;          // 2048 = 16 o x 128 t
        int o = flat >> 7, t = flat & 127;
        size_t base = ((size_t)b * NCH + oge + o) * NFR + t;
        float v = 0.f;
#pragma unroll
        for (int sl = 0; sl < 8; ++sl) v += yp[(size_t)sl * 524288 + base];
        v += encb[l * NCH + oge + o];
        v = (v > 0.f) ? v : 0.2f * v;
        float r = hin[base] + v;
        hout[base] = r;
        T[o * 132 + t] = r;
      }
      __syncthreads();
      if (tid < 16) {   // channel-mean z (layer 7's write is consumed)
        float sm = 0.f;
#pragma unroll 8
        for (int t = 0; t < 128; ++t) sm += T[tid * 132 + t];
        zbuf[b * NCH + oge + tid] = sm * (1.f / 128.f);
      }
#pragma unroll
      for (int j = 0; j < 8; ++j) {
        int flat = j * 256 + tid;
        int t = flat >> 4, o = flat & 15;
        ushort hi, lo;
        split_bf(T[o * 132 + t], hi, lo);
        size_t tidx = ((size_t)b * 192 + t) * 1024 + oge + o;
        eTh[tidx] = hi;
        eTl[tidx] = lo;
      }
    }

    target += 256;
    gsync(cnt, target);
  }
}

// ---------------- f32 GEMM (enc only), K-split partials ----------------
template <int TAPS, int D, int KTOT, int SPLIT, int MROWS>
__global__ __launch_bounds__(256, 2) void gemm_f32(const float* __restrict__ hin,
                                                   const float* __restrict__ W,
                                                   float* __restrict__ yp) {
  __shared__ float As[64][68];
  __shared__ float Bs[64][132];
  int tid = threadIdx.x;
  int og = blockIdx.x * 64;
  int b = blockIdx.y;
  int s = blockIdx.z;
  const float* hb = hin + (size_t)b * (NCH * NFR);
  int tx = tid & 15;
  int ty = tid >> 4;
  float acc[4][8] = {};
  const int KS = KTOT / SPLIT;
  for (int kt = 0; kt < KS / 64; ++kt) {
    int k0 = s * KS + kt * 64;
    __syncthreads();
    {
      int r = tid >> 2;
      int seg = (tid & 3) * 16;
      const float4* src = (const float4*)(W + (size_t)(og + r) * KTOT + k0 + seg);
#pragma unroll
      for (int q = 0; q < 4; ++q) {
        float4 v = src[q];
        int row = seg + 4 * q;
#pragma unroll
        for (int i = 0; i < 4; ++i) {
          int rr = row + i;
          int col = r ^ (((rr >> 4) & 1) << 2);
          float val = (i == 0) ? v.x : (i == 1) ? v.y : (i == 2) ? v.z : v.w;
          As[rr][col] = val;
        }
      }
    }
    {
      int r = tid >> 2;
      int tq = (tid & 3) * 32;
      int c = k0 + r;
      const float4* src = (const float4*)(hb + (size_t)c * NFR + tq);
#pragma unroll
      for (int q = 0; q < 8; ++q) *(float4*)&Bs[r][tq + 4 * q] = src[q];
    }
    __syncthreads();
#pragma unroll 8
    for (int kk = 0; kk < 64; ++kk) {
      int ca = (ty * 4) ^ (((kk >> 4) & 1) << 2);
      float4 a0 = *(const float4*)&As[kk][ca];
      float4 b0 = *(const float4*)&Bs[kk][tx * 4];
      float4 b1 = *(const float4*)&Bs[kk][tx * 4 + 64];
      float av[4] = {a0.x, a0.y, a0.z, a0.w};
      float bv[8] = {b0.x, b0.y, b0.z, b0.w, b1.x, b1.y, b1.z, b1.w};
#pragma unroll
      for (int i = 0; i < 4; ++i)
#pragma unroll
        for (int j = 0; j < 8; ++j)
          acc[i][j] += av[i] * bv[j];
    }
  }
  float* ypb = yp + (size_t)s * (NB * MROWS * NFR) + (size_t)b * MROWS * NFR;
#pragma unroll
  for (int i = 0; i < 4; ++i) {
    int o = og + ty * 4 + i;
    *(float4*)&ypb[o * NFR + tx * 4] = (float4){acc[i][0], acc[i][1], acc[i][2], acc[i][3]};
    *(float4*)&ypb[o * NFR + tx * 4 + 64] = (float4){acc[i][4], acc[i][5], acc[i][6], acc[i][7]};
  }
}

// ---------------- enc partial sum: enc = sum_16 ep + bias (full machine) ----------------
__global__ void encsum_kernel(const float* __restrict__ ep, const float* __restrict__ upb,
                              float* __restrict__ enc) {
  int b = blockIdx.y;
  int i4 = blockIdx.x * 256 + threadIdx.x;   // float4 index within batch (8192)
  int i = i4 * 4;
  float bv = upb[i >> 7];
  float4 s = {bv, bv, bv, bv};
#pragma unroll
  for (int sl = 0; sl < 16; ++sl) {
    float4 p = *(const float4*)&ep[(size_t)sl * 131072 + b * 32768 + i];
    s.x += p.x; s.y += p.y; s.z += p.z; s.w += p.w;
  }
  *(float4*)&enc[b * 32768 + i] = s;
}

// ---------------- MLP heads only (z precomputed); 64 threads/block ----------------
__global__ __launch_bounds__(64) void dense_mlp_kernel(
    const float* __restrict__ zbuf,
    const float* __restrict__ latw, const float* __restrict__ latb,
    const float* __restrict__ rw, const float* __restrict__ rb,
    const float* __restrict__ rg, const float* __restrict__ rbe,
    const float* __restrict__ rowt, const float* __restrict__ rob,
    const float* __restrict__ mw, const float* __restrict__ mb,
    const float* __restrict__ mg, const float* __restrict__ mbe,
    const float* __restrict__ mow, const float* __restrict__ mob,
    float* __restrict__ room, float* __restrict__ mixv) {
  int b = blockIdx.x;
  int tid = threadIdx.x;
  const float* z = zbuf + b * NCH;
  int j = tid & 15;
  int p = tid >> 4;
  float dsum = 0.f;
  for (int c = p * 256; c < p * 256 + 256; ++c)
    dsum += z[c] * latw[c * 16 + j];
  dsum += __shfl_xor(dsum, 16);
  dsum += __shfl_xor(dsum, 32);
  float dj = dsum + latb[j];
  float sq = dj * dj;
  sq += __shfl_xor(sq, 1, 16);
  sq += __shfl_xor(sq, 2, 16);
  sq += __shfl_xor(sq, 4, 16);
  sq += __shfl_xor(sq, 8, 16);
  float a = dj / (sqrtf(sq) + 1e-8f);

  const float* W = rw;  const float* Bb = rb;
  const float* G = rg;  const float* Be = rbe;
  for (int which = 0; which < 2; ++which) {
    float v = a;
    for (int l = 0; l < 3; ++l) {
      float accv = Bb[l * 16 + j];
      for (int k = 0; k < 16; ++k) {
        float ak = __shfl(v, (tid & 48) | k);
        accv += ak * W[(l * 16 + k) * 16 + j];
      }
      float mu = accv;
      mu += __shfl_xor(mu, 1, 16); mu += __shfl_xor(mu, 2, 16);
      mu += __shfl_xor(mu, 4, 16); mu += __shfl_xor(mu, 8, 16);
      mu *= (1.f / 16.f);
      float dv = accv - mu;
      float var = dv * dv;
      var += __shfl_xor(var, 1, 16); var += __shfl_xor(var, 2, 16);
      var += __shfl_xor(var, 4, 16); var += __shfl_xor(var, 8, 16);
      var *= (1.f / 16.f);
      float xn = dv * rsqrtf(var + 1e-5f) * G[l * 16 + j] + Be[l * 16 + j];
      v = (xn > 0.f) ? xn : 0.2f * xn;
    }
    if (which == 0) {
      int r = tid & 7;
      float logit = rob[r];
      for (int k = 0; k < 16; ++k) {
        float ak = __shfl(v, (tid & 48) | k);
        logit += ak * rowt[k * 8 + r];
      }
      float mx = logit;
      mx = fmaxf(mx, __shfl_xor(mx, 1, 8));
      mx = fmaxf(mx, __shfl_xor(mx, 2, 8));
      mx = fmaxf(mx, __shfl_xor(mx, 4, 8));
      float e = expf(logit - mx);
      float se = e;
      se += __shfl_xor(se, 1, 8);
      se += __shfl_xor(se, 2, 8);
      se += __shfl_xor(se, 4, 8);
      if (tid < 8) room[b * 8 + r] = e / se;
      W = mw; Bb = mb; G = mg; Be = mbe;
    } else {
      float logit = mob[0];
      for (int k = 0; k < 16; ++k) {
        float ak = __shfl(v, (tid & 48) | k);
        logit += ak * mow[k];
      }
      if (tid == 0) mixv[b] = 1.f / (1.f + expf(-logit));
    }
  }
}

// ---------------- top-16 (jax tie semantics) over pre-summed enc ----------------
__global__ __launch_bounds__(256) void topk_kernel(const float* __restrict__ enc,
                                                   float* __restrict__ vals,
                                                   int* __restrict__ chs,
                                                   int* __restrict__ tps) {
  __shared__ float swv[4];
  __shared__ int swi[4];
  int b = blockIdx.x;
  int tid = threadIdx.x;
  const float* e = enc + b * 32768;
  float lv[16];
  int li[16];
#pragma unroll
  for (int q = 0; q < 16; ++q) { lv[q] = -INFINITY; li[q] = 0x7fffffff; }
  for (int i = tid; i < 32768; i += 256) {
    float v = e[i];
    if (v > lv[15]) {
      float cv = v; int ci = i;
#pragma unroll
      for (int q = 0; q < 16; ++q) {
        if (cv > lv[q]) {
          float tv = lv[q]; int ti = li[q];
          lv[q] = cv; li[q] = ci;
          cv = tv; ci = ti;
        }
      }
    }
  }
  for (int round = 0; round < 16; ++round) {
    float cv = lv[0];
    int ci = li[0];
#pragma unroll
    for (int off = 1; off < 64; off <<= 1) {
      float ov = __shfl_xor(cv, off);
      int oi = __shfl_xor(ci, off);
      if (ov > cv || (ov == cv && oi < ci)) { cv = ov; ci = oi; }
    }
    if ((tid & 63) == 0) { swv[tid >> 6] = cv; swi[tid >> 6] = ci; }
    __syncthreads();
    float wv = swv[0]; int wi = swi[0];
#pragma unroll
    for (int w = 1; w < 4; ++w) {
      float v2 = swv[w]; int i2 = swi[w];
      if (v2 > wv || (v2 == wv && i2 < wi)) { wv = v2; wi = i2; }
    }
    if (tid == 0) {
      vals[b * 16 + round] = (wv > 0.f) ? wv : 0.f;
      chs[b * 16 + round] = wi >> 7;
      tps[b * 16 + round] = (wi & 127) * 256;
    }
    if (li[0] == wi) {
#pragma unroll
      for (int q = 0; q < 15; ++q) { lv[q] = lv[q + 1]; li[q] = li[q + 1]; }
      lv[15] = -INFINITY; li[15] = 0x7fffffff;
    }
    __syncthreads();
  }
}

// ---------------- dry + impulse fused ----------------
__global__ void dryimp_kernel(const float* __restrict__ atoms,
                              const float* __restrict__ vals, const int* __restrict__ chs,
                              const int* __restrict__ tps, const float* __restrict__ imps,
                              const float* __restrict__ room,
                              float* __restrict__ dry, float* __restrict__ imp) {
  int b = blockIdx.y;
  int n = blockIdx.x * 256 + threadIdx.x;
  float acc = 0.f;
#pragma unroll 4
  for (int j = 0; j < 16; ++j) {
    float v = vals[b * 16 + j];
    int tp = tps[b * 16 + j];
    int ch = chs[b * 16 + j];
    if (v != 0.f && n >= tp)
      acc += v * atoms[(size_t)ch * NSMP + (n - tp)];
  }
  dry[b * NSMP + n] = acc;
  float ia = 0.f;
#pragma unroll
  for (int r = 0; r < 8; ++r)
    ia += room[b * 8 + r] * imps[r * NSMP + n];
  imp[b * NSMP + n] = ia;
}

// ---------------- wet partials (no atomics) ----------------
#define IS(a) is[(a) + ((a) >> 5)]
__global__ __launch_bounds__(256) void wet_kernel(const float* __restrict__ dry,
                                                  const float* __restrict__ impulse,
                                                  float* __restrict__ wp) {
  int s = blockIdx.x;
  int nt = blockIdx.y;
  int b = blockIdx.z;
  if (s > nt) return;
  __shared__ float is[4224];
  __shared__ float dsr[2048];
  int tid = threadIdx.x;
  int n0 = nt * 2048;
  int m0 = s * 2048;
  int base = n0 - m0 - 2047;
  const float* impb = impulse + b * NSMP;
  for (int k = tid; k < 4096; k += 256) {
    int idx = base + k;
    IS(k) = (idx >= 0 && idx < NSMP) ? impb[idx] : 0.f;
  }
  for (int i = tid; i < 2048; i += 256)
    dsr[i] = dry[b * NSMP + m0 + 2047 - i];
  __syncthreads();
  int aw = tid * 8;
  float w[8];
#pragma unroll
  for (int j = 0; j < 8; ++j) w[j] = IS(aw + j);
  float acc[8] = {};
  for (int jb = 0; jb < 2048; jb += 8) {
    float4 d0 = *(const float4*)&dsr[jb];
    float4 d1 = *(const float4*)&dsr[jb + 4];
    float dv[8] = {d0.x, d0.y, d0.z, d0.w, d1.x, d1.y, d1.z, d1.w};
#pragma unroll
    for (int e = 0; e < 8; ++e) {
      float dval = dv[e];
#pragma unroll
      for (int i = 0; i < 8; ++i)
        acc[i] += dval * w[(e + i) & 7];
      w[e] = IS(aw + jb + e + 8);
    }
  }
  float* dst = wp + (size_t)s * (NB * NSMP) + (size_t)b * NSMP + n0 + aw;
  *(float4*)dst = (float4){acc[0], acc[1], acc[2], acc[3]};
  *(float4*)(dst + 4) = (float4){acc[4], acc[5], acc[6], acc[7]};
}

// ---------------- out = dry*mix + (sum_s wp[s])*(1-mix) ----------------
__global__ void out_kernel(const float* __restrict__ dry, const float* __restrict__ wp,
                           const float* __restrict__ mixv, float* __restrict__ out) {
  int b = blockIdx.y;
  int n = blockIdx.x * 256 + threadIdx.x;
  float m = mixv[b];
  float wv = 0.f;
  int smax = n >> 11;
  for (int s = 0; s <= smax; ++s)
    wv += wp[(size_t)s * (NB * NSMP) + b * NSMP + n];
  out[b * NSMP + n] = dry[b * NSMP + n] * m + wv * (1.f - m);
}

extern "C" void kernel_launch(void* const* d_in, const int* in_sizes, int n_in,
                              void* d_out, int out_size, void* d_ws, size_t ws_size,
                              hipStream_t stream) {
  const float* x    = (const float*)d_in[0];
  const float* atoms= (const float*)d_in[1];
  const float* encw = (const float*)d_in[2];
  const float* encb = (const float*)d_in[3];
  const float* upw  = (const float*)d_in[4];
  const float* upb  = (const float*)d_in[5];
  const float* latw = (const float*)d_in[6];
  const float* latb = (const float*)d_in[7];
  const float* rw   = (const float*)d_in[8];
  const float* rb   = (const float*)d_in[9];
  const float* rg   = (const float*)d_in[10];
  const float* rbe  = (const float*)d_in[11];
  const float* rowt = (const float*)d_in[12];
  const float* rob  = (const float*)d_in[13];
  const float* mw   = (const float*)d_in[14];
  const float* mb   = (const float*)d_in[15];
  const float* mg   = (const float*)d_in[16];
  const float* mbe  = (const float*)d_in[17];
  const float* mow  = (const float*)d_in[18];
  const float* mob  = (const float*)d_in[19];
  const float* imps = (const float*)d_in[20];

  float* f    = (float*)d_ws;
  float* h0   = f;                 // 524288
  float* h1   = f + 524288;        // 524288
  float* yp   = f + 1048576;       // 8 x 524288 (conv split-K partials)
  float* ep   = yp;                // 16 x 131072 enc partials alias (post-conv)
  float* wp   = yp + 524288;       // 16 x 131072 wet partials alias (post-topk)
  float* dry  = f + 5242880;       // 131072
  float* imp  = f + 5373952;       // 131072
  float* encf = f + 5505024;       // 131072 (summed enc)
  float* room = f + 5636096;       // 32
  float* mixv = f + 5636128;       // 4
  float* vals = f + 5636160;       // 64
  int*   chs  = (int*)(f + 5636224);
  int*   tps  = (int*)(f + 5636288);
  float* zbuf = f + 5636352;       // 4096 (channel means)
  unsigned* cnt = (unsigned*)(f + 5640448);  // barrier counter
  // bf16 regions
  ushort* w0h  = (ushort*)(f + 6000000);   // 8 x 1024 x 1024 each
  ushort* w0l  = w0h + 8388608;
  ushort* w1h  = w0l + 8388608;
  ushort* w1l  = w1h + 8388608;
  ushort* hTh0 = w1l + 8388608;            // [4][192][1024]
  ushort* hTl0 = hTh0 + 786432;
  ushort* hTh1 = hTl0 + 786432;
  ushort* hTl1 = hTh1 + 786432;

  hipMemsetAsync(cnt, 0, sizeof(unsigned), stream);
  wsplit_kernel<<<16384, 256, 0, stream>>>(encw, w0h, w0l, w1h, w1l);
  stft_kernel<<<512, 256, 0, stream>>>(x, h0, hTh0, hTl0, hTh1, hTl1);

  // fused 8-layer conv stack (persistent 256-block kernel, manual device-scope barrier)
  conv_stack<<<256, 256, 0, stream>>>(w0h, w0l, w1h, w1l, encb, h0, h1,
                                      hTh0, hTl0, hTh1, hTl1, yp, zbuf, cnt);
  // final h in h0; zbuf holds layer-7 channel means

  dense_mlp_kernel<<<4, 64, 0, stream>>>(zbuf, latw, latb, rw, rb, rg, rbe, rowt, rob,
                                         mw, mb, mg, mbe, mow, mob, room, mixv);
  gemm_f32<1, 0, 1024, 16, 256><<<dim3(4, 4, 16), 256, 0, stream>>>(h0, upw, ep);
  encsum_kernel<<<dim3(32, 4), 256, 0, stream>>>(ep, upb, encf);
  topk_kernel<<<4, 256, 0, stream>>>(encf, vals, chs, tps);
  dryimp_kernel<<<dim3(128, 4), 256, 0, stream>>>(atoms, vals, chs, tps, imps, room, dry, imp);
  wet_kernel<<<dim3(16, 16, 4), 256, 0, stream>>>(dry, imp, wp);
  out_kernel<<<dim3(128, 4), 256, 0, stream>>>(dry, wp, mixv, (float*)d_out);
}

// Round 13
// 563.068 us; speedup vs baseline: 1.7962x; 1.7962x over previous
//
#include <hip/hip_runtime.h>
#include <hip/hip_bf16.h>
#include <math.h>

#define NSMP 32768
#define NFR 128
#define NCH 1024
#define NB 4

typedef __attribute__((ext_vector_type(8))) short short8;
typedef __attribute__((ext_vector_type(4))) float f32x4;
typedef unsigned short ushort;

__device__ __forceinline__ void split_bf(float v, ushort& h, ushort& l) {
  __hip_bfloat16 bh = __float2bfloat16(v);
  float r = v - __bfloat162float(bh);
  __hip_bfloat16 bl = __float2bfloat16(r);
  h = *reinterpret_cast<ushort*>(&bh);
  l = *reinterpret_cast<ushort*>(&bl);
}

// ---------------- STFT: emits h (f32) + transposed hi/lo bf16 hT[t][c]; zeros hT pad rows ----------------
__global__ __launch_bounds__(256) void stft_kernel(const float* __restrict__ x,
                                                   float* __restrict__ h,
                                                   ushort* __restrict__ hTh,
                                                   ushort* __restrict__ hTl,
                                                   ushort* __restrict__ hTh1,
                                                   ushort* __restrict__ hTl1) {
  __shared__ float re[2048];
  __shared__ float im[2048];
  __shared__ float twr[1024];
  __shared__ float twi[1024];
  int bid = blockIdx.x;
  int b = bid >> 7;
  int f = bid & 127;
  int tid = threadIdx.x;
  const float TWO_PI = 6.28318530717958647692f;
  if (f < 64) {
    size_t pidx = ((size_t)b * 192 + 128 + f) * 1024 + tid * 4;
    uint2 z = {0u, 0u};
    *(uint2*)&hTh[pidx] = z;  *(uint2*)&hTl[pidx] = z;
    *(uint2*)&hTh1[pidx] = z; *(uint2*)&hTl1[pidx] = z;
  }
  for (int k = tid; k < 1024; k += 256) {
    float ang = -TWO_PI * (float)k / 2048.0f;
    float sn, cs;
    sincosf(ang, &sn, &cs);
    twr[k] = cs; twi[k] = sn;
  }
  for (int i = tid; i < 2048; i += 256) {
    int rev = (int)(__brev((unsigned)i) >> 21);
    int pos = f * 256 + rev;
    float v = (pos < NSMP) ? x[b * NSMP + pos] : 0.f;
    float w = 0.5f - 0.5f * cosf(TWO_PI * (float)rev / 2047.0f);  // jnp.hanning(2048)
    re[i] = v * w;
    im[i] = 0.f;
  }
  __syncthreads();
  for (int s = 0; s < 11; ++s) {
    for (int q = 0; q < 4; ++q) {
      int bi = tid + q * 256;
      int half = 1 << s;
      int j = bi & (half - 1);
      int i0 = ((bi >> s) << (s + 1)) | j;
      int i1 = i0 + half;
      int ti = j << (10 - s);
      float cs = twr[ti], sn = twi[ti];
      float ur = re[i0], ui = im[i0];
      float vr = re[i1], vi = im[i1];
      float tr = vr * cs - vi * sn;
      float tti = vr * sn + vi * cs;
      re[i0] = ur + tr; im[i0] = ui + tti;
      re[i1] = ur - tr; im[i1] = ui - tti;
    }
    __syncthreads();
  }
  for (int k = tid; k < 1024; k += 256) {
    float m = sqrtf(re[k] * re[k] + im[k] * im[k]);
    h[(b * NCH + k) * NFR + f] = m;
    ushort hi, lo;
    split_bf(m, hi, lo);
    size_t tidx = ((size_t)b * 192 + f) * 1024 + k;
    hTh[tidx] = hi;
    hTl[tidx] = lo;
  }
}

// ---------------- split encw into per-tap hi/lo bf16 weight arrays ----------------
__global__ __launch_bounds__(256) void wsplit_kernel(const float* __restrict__ encw,
                                                     ushort* __restrict__ w0h, ushort* __restrict__ w0l,
                                                     ushort* __restrict__ w1h, ushort* __restrict__ w1l) {
  size_t F = (size_t)blockIdx.x * 256 + threadIdx.x;  // 4,194,304 float4s
  float4 v = ((const float4*)encw)[F];
  size_t lo_idx = F >> 9;            // l*1024+o
  int c0 = (int)(F & 511) * 2;
  size_t base = lo_idx * 1024 + c0;
  ushort h0, l0, h1, l1;
  split_bf(v.x, h0, l0);
  split_bf(v.z, h1, l1);
  *(ushort2*)&w0h[base] = (ushort2){h0, h1};
  *(ushort2*)&w0l[base] = (ushort2){l0, l1};
  split_bf(v.y, h0, l0);
  split_bf(v.w, h1, l1);
  *(ushort2*)&w1h[base] = (ushort2){h0, h1};
  *(ushort2*)&w1l[base] = (ushort2){l0, l1};
}

// ---------------- conv GEMM: split-bf16 3-product MFMA, DIRECT global->reg operands (no LDS) ----------------
// block: 128 o x 128 t (one batch), K-slice s (128 c x 2 taps). 4 waves, 64x64 quadrants.
// Operands are L2-resident (W 8MB/layer, hT 1.5MB/batch); each frag = lane-contiguous 16B load.
// Accumulation order identical to round 9/10: tap 0 chunks c0..c3, then tap 1.
__global__ __launch_bounds__(256) void conv_mfma(const ushort* __restrict__ hTh,
                                                 const ushort* __restrict__ hTl,
                                                 const ushort* __restrict__ w0h, const ushort* __restrict__ w0l,
                                                 const ushort* __restrict__ w1h, const ushort* __restrict__ w1l,
                                                 int D, float* __restrict__ yp) {
  int tid = threadIdx.x;
  int og = blockIdx.x * 128;
  int b = blockIdx.y;
  int s = blockIdx.z;
  int wid = tid >> 6, lane = tid & 63;
  int wr = (wid >> 1) * 64, wc = (wid & 1) * 64;
  int lr = lane & 15, lk = lane >> 4;

  f32x4 acc[4][4];
#pragma unroll
  for (int m = 0; m < 4; ++m)
#pragma unroll
    for (int n = 0; n < 4; ++n) acc[m][n] = (f32x4){0.f, 0.f, 0.f, 0.f};

  const ushort* hb_h = hTh + (size_t)b * 192 * 1024;
  const ushort* hb_l = hTl + (size_t)b * 192 * 1024;
  int cbase = s * 128 + lk * 8;   // per-lane k-granule base within the slice

#pragma unroll
  for (int tap = 0; tap < 2; ++tap) {
    const ushort* Wh = tap ? w1h : w0h;
    const ushort* Wl = tap ? w1l : w0l;
    int rowoff = tap ? D : 0;
#pragma unroll
    for (int kc = 0; kc < 4; ++kc) {
      int c0 = cbase + kc * 32;
      short8 ah[4], al[4], bh[4], bl[4];
#pragma unroll
      for (int m = 0; m < 4; ++m) {
        size_t off = (size_t)(og + wr + m * 16 + lr) * 1024 + c0;
        ah[m] = *(const short8*)(Wh + off);
        al[m] = *(const short8*)(Wl + off);
      }
#pragma unroll
      for (int n = 0; n < 4; ++n) {
        size_t off = (size_t)(wc + n * 16 + lr + rowoff) * 1024 + c0;  // rows <192; pad rows are zero
        bh[n] = *(const short8*)(hb_h + off);
        bl[n] = *(const short8*)(hb_l + off);
      }
#pragma unroll
      for (int m = 0; m < 4; ++m)
#pragma unroll
        for (int n = 0; n < 4; ++n) {
          acc[m][n] = __builtin_amdgcn_mfma_f32_16x16x32_bf16(ah[m], bh[n], acc[m][n], 0, 0, 0);
          acc[m][n] = __builtin_amdgcn_mfma_f32_16x16x32_bf16(ah[m], bl[n], acc[m][n], 0, 0, 0);
          acc[m][n] = __builtin_amdgcn_mfma_f32_16x16x32_bf16(al[m], bh[n], acc[m][n], 0, 0, 0);
        }
    }
  }

  float* dst = yp + (size_t)(s * 4 + b) * 131072;
#pragma unroll
  for (int m = 0; m < 4; ++m)
#pragma unroll
    for (int n = 0; n < 4; ++n)
#pragma unroll
      for (int r = 0; r < 4; ++r) {
        int orow = og + wr + m * 16 + lk * 4 + r;  // C/D: row=(lane>>4)*4+reg
        int col = wc + n * 16 + lr;                //      col=lane&15
        dst[orow * 128 + col] = acc[m][n][r];
      }
}

// ---------------- conv epilogue: residual+bias+lrelu, emit f32 h + hi/lo hT + channel-mean z ----------------
__global__ __launch_bounds__(256) void conv_epi(const float* __restrict__ yp,
                                                const float* __restrict__ hin,
                                                const float* __restrict__ bias,
                                                float* __restrict__ hout,
                                                ushort* __restrict__ hTh,
                                                ushort* __restrict__ hTl,
                                                float* __restrict__ zbuf) {
  __shared__ float T[16][132];
  int og = blockIdx.x * 16;
  int b = blockIdx.y;
  int tid = threadIdx.x;
#pragma unroll
  for (int j = 0; j < 8; ++j) {
    int flat = j * 256 + tid;          // 2048 = 16 o x 128 t
    int o = flat >> 7, t = flat & 127;
    size_t base = ((size_t)b * NCH + og + o) * NFR + t;
    float v = 0.f;
#pragma unroll
    for (int sl = 0; sl < 8; ++sl) v += yp[(size_t)sl * 524288 + base];
    v += bias[og + o];
    v = (v > 0.f) ? v : 0.2f * v;
    float r = hin[base] + v;
    hout[base] = r;
    T[o][t] = r;
  }
  __syncthreads();
  if (tid < 16) {   // z[b][c] = mean_t h  (layer 7's write is the one consumed)
    float sm = 0.f;
#pragma unroll 8
    for (int t = 0; t < 128; ++t) sm += T[tid][t];
    zbuf[b * NCH + og + tid] = sm * (1.f / 128.f);
  }
#pragma unroll
  for (int j = 0; j < 8; ++j) {
    int flat = j * 256 + tid;
    int t = flat >> 4, o = flat & 15;
    ushort hi, lo;
    split_bf(T[o][t], hi, lo);
    size_t tidx = ((size_t)b * 192 + t) * 1024 + og + o;
    hTh[tidx] = hi;
    hTl[tidx] = lo;
  }
}

// ---------------- f32 GEMM (enc only), K-split partials ----------------
template <int TAPS, int D, int KTOT, int SPLIT, int MROWS>
__global__ __launch_bounds__(256, 2) void gemm_f32(const float* __restrict__ hin,
                                                   const float* __restrict__ W,
                                                   float* __restrict__ yp) {
  __shared__ float As[64][68];
  __shared__ float Bs[64][132];
  int tid = threadIdx.x;
  int og = blockIdx.x * 64;
  int b = blockIdx.y;
  int s = blockIdx.z;
  const float* hb = hin + (size_t)b * (NCH * NFR);
  int tx = tid & 15;
  int ty = tid >> 4;
  float acc[4][8] = {};
  const int KS = KTOT / SPLIT;
  for (int kt = 0; kt < KS / 64; ++kt) {
    int k0 = s * KS + kt * 64;
    __syncthreads();
    {
      int r = tid >> 2;
      int seg = (tid & 3) * 16;
      const float4* src = (const float4*)(W + (size_t)(og + r) * KTOT + k0 + seg);
#pragma unroll
      for (int q = 0; q < 4; ++q) {
        float4 v = src[q];
        int row = seg + 4 * q;
#pragma unroll
        for (int i = 0; i < 4; ++i) {
          int rr = row + i;
          int col = r ^ (((rr >> 4) & 1) << 2);
          float val = (i == 0) ? v.x : (i == 1) ? v.y : (i == 2) ? v.z : v.w;
          As[rr][col] = val;
        }
      }
    }
    {
      int r = tid >> 2;
      int tq = (tid & 3) * 32;
      int c = k0 + r;
      const float4* src = (const float4*)(hb + (size_t)c * NFR + tq);
#pragma unroll
      for (int q = 0; q < 8; ++q) *(float4*)&Bs[r][tq + 4 * q] = src[q];
    }
    __syncthreads();
#pragma unroll 8
    for (int kk = 0; kk < 64; ++kk) {
      int ca = (ty * 4) ^ (((kk >> 4) & 1) << 2);
      float4 a0 = *(const float4*)&As[kk][ca];
      float4 b0 = *(const float4*)&Bs[kk][tx * 4];
      float4 b1 = *(const float4*)&Bs[kk][tx * 4 + 64];
      float av[4] = {a0.x, a0.y, a0.z, a0.w};
      float bv[8] = {b0.x, b0.y, b0.z, b0.w, b1.x, b1.y, b1.z, b1.w};
#pragma unroll
      for (int i = 0; i < 4; ++i)
#pragma unroll
        for (int j = 0; j < 8; ++j)
          acc[i][j] += av[i] * bv[j];
    }
  }
  float* ypb = yp + (size_t)s * (NB * MROWS * NFR) + (size_t)b * MROWS * NFR;
#pragma unroll
  for (int i = 0; i < 4; ++i) {
    int o = og + ty * 4 + i;
    *(float4*)&ypb[o * NFR + tx * 4] = (float4){acc[i][0], acc[i][1], acc[i][2], acc[i][3]};
    *(float4*)&ypb[o * NFR + tx * 4 + 64] = (float4){acc[i][4], acc[i][5], acc[i][6], acc[i][7]};
  }
}

// ---------------- enc partial sum: enc = sum_16 ep + bias (full machine) ----------------
__global__ void encsum_kernel(const float* __restrict__ ep, const float* __restrict__ upb,
                              float* __restrict__ enc) {
  int b = blockIdx.y;
  int i4 = blockIdx.x * 256 + threadIdx.x;   // float4 index within batch (8192)
  int i = i4 * 4;
  float bv = upb[i >> 7];
  float4 s = {bv, bv, bv, bv};
#pragma unroll
  for (int sl = 0; sl < 16; ++sl) {
    float4 p = *(const float4*)&ep[(size_t)sl * 131072 + b * 32768 + i];
    s.x += p.x; s.y += p.y; s.z += p.z; s.w += p.w;
  }
  *(float4*)&enc[b * 32768 + i] = s;
}

// ---------------- MLP heads only (z precomputed); 64 threads/block ----------------
__global__ __launch_bounds__(64) void dense_mlp_kernel(
    const float* __restrict__ zbuf,
    const float* __restrict__ latw, const float* __restrict__ latb,
    const float* __restrict__ rw, const float* __restrict__ rb,
    const float* __restrict__ rg, const float* __restrict__ rbe,
    const float* __restrict__ rowt, const float* __restrict__ rob,
    const float* __restrict__ mw, const float* __restrict__ mb,
    const float* __restrict__ mg, const float* __restrict__ mbe,
    const float* __restrict__ mow, const float* __restrict__ mob,
    float* __restrict__ room, float* __restrict__ mixv) {
  int b = blockIdx.x;
  int tid = threadIdx.x;
  const float* z = zbuf + b * NCH;
  int j = tid & 15;
  int p = tid >> 4;
  float dsum = 0.f;
  for (int c = p * 256; c < p * 256 + 256; ++c)
    dsum += z[c] * latw[c * 16 + j];
  dsum += __shfl_xor(dsum, 16);
  dsum += __shfl_xor(dsum, 32);
  float dj = dsum + latb[j];
  float sq = dj * dj;
  sq += __shfl_xor(sq, 1, 16);
  sq += __shfl_xor(sq, 2, 16);
  sq += __shfl_xor(sq, 4, 16);
  sq += __shfl_xor(sq, 8, 16);
  float a = dj / (sqrtf(sq) + 1e-8f);

  const float* W = rw;  const float* Bb = rb;
  const float* G = rg;  const float* Be = rbe;
  for (int which = 0; which < 2; ++which) {
    float v = a;
    for (int l = 0; l < 3; ++l) {
      float accv = Bb[l * 16 + j];
      for (int k = 0; k < 16; ++k) {
        float ak = __shfl(v, (tid & 48) | k);
        accv += ak * W[(l * 16 + k) * 16 + j];
      }
      float mu = accv;
      mu += __shfl_xor(mu, 1, 16); mu += __shfl_xor(mu, 2, 16);
      mu += __shfl_xor(mu, 4, 16); mu += __shfl_xor(mu, 8, 16);
      mu *= (1.f / 16.f);
      float dv = accv - mu;
      float var = dv * dv;
      var += __shfl_xor(var, 1, 16); var += __shfl_xor(var, 2, 16);
      var += __shfl_xor(var, 4, 16); var += __shfl_xor(var, 8, 16);
      var *= (1.f / 16.f);
      float xn = dv * rsqrtf(var + 1e-5f) * G[l * 16 + j] + Be[l * 16 + j];
      v = (xn > 0.f) ? xn : 0.2f * xn;
    }
    if (which == 0) {
      int r = tid & 7;
      float logit = rob[r];
      for (int k = 0; k < 16; ++k) {
        float ak = __shfl(v, (tid & 48) | k);
        logit += ak * rowt[k * 8 + r];
      }
      float mx = logit;
      mx = fmaxf(mx, __shfl_xor(mx, 1, 8));
      mx = fmaxf(mx, __shfl_xor(mx, 2, 8));
      mx = fmaxf(mx, __shfl_xor(mx, 4, 8));
      float e = expf(logit - mx);
      float se = e;
      se += __shfl_xor(se, 1, 8);
      se += __shfl_xor(se, 2, 8);
      se += __shfl_xor(se, 4, 8);
      if (tid < 8) room[b * 8 + r] = e / se;
      W = mw; Bb = mb; G = mg; Be = mbe;
    } else {
      float logit = mob[0];
      for (int k = 0; k < 16; ++k) {
        float ak = __shfl(v, (tid & 48) | k);
        logit += ak * mow[k];
      }
      if (tid == 0) mixv[b] = 1.f / (1.f + expf(-logit));
    }
  }
}

// ---------------- top-16 (jax tie semantics) over pre-summed enc ----------------
__global__ __launch_bounds__(256) void topk_kernel(const float* __restrict__ enc,
                                                   float* __restrict__ vals,
                                                   int* __restrict__ chs,
                                                   int* __restrict__ tps) {
  __shared__ float swv[4];
  __shared__ int swi[4];
  int b = blockIdx.x;
  int tid = threadIdx.x;
  const float* e = enc + b * 32768;
  float lv[16];
  int li[16];
#pragma unroll
  for (int q = 0; q < 16; ++q) { lv[q] = -INFINITY; li[q] = 0x7fffffff; }
  for (int i = tid; i < 32768; i += 256) {
    float v = e[i];
    if (v > lv[15]) {
      float cv = v; int ci = i;
#pragma unroll
      for (int q = 0; q < 16; ++q) {
        if (cv > lv[q]) {
          float tv = lv[q]; int ti = li[q];
          lv[q] = cv; li[q] = ci;
          cv = tv; ci = ti;
        }
      }
    }
  }
  for (int round = 0; round < 16; ++round) {
    float cv = lv[0];
    int ci = li[0];
#pragma unroll
    for (int off = 1; off < 64; off <<= 1) {
      float ov = __shfl_xor(cv, off);
      int oi = __shfl_xor(ci, off);
      if (ov > cv || (ov == cv && oi < ci)) { cv = ov; ci = oi; }
    }
    if ((tid & 63) == 0) { swv[tid >> 6] = cv; swi[tid >> 6] = ci; }
    __syncthreads();
    float wv = swv[0]; int wi = swi[0];
#pragma unroll
    for (int w = 1; w < 4; ++w) {
      float v2 = swv[w]; int i2 = swi[w];
      if (v2 > wv || (v2 == wv && i2 < wi)) { wv = v2; wi = i2; }
    }
    if (tid == 0) {
      vals[b * 16 + round] = (wv > 0.f) ? wv : 0.f;
      chs[b * 16 + round] = wi >> 7;
      tps[b * 16 + round] = (wi & 127) * 256;
    }
    if (li[0] == wi) {
#pragma unroll
      for (int q = 0; q < 15; ++q) { lv[q] = lv[q + 1]; li[q] = li[q + 1]; }
      lv[15] = -INFINITY; li[15] = 0x7fffffff;
    }
    __syncthreads();
  }
}

// ---------------- dry + impulse fused ----------------
__global__ void dryimp_kernel(const float* __restrict__ atoms,
                              const float* __restrict__ vals, const int* __restrict__ chs,
                              const int* __restrict__ tps, const float* __restrict__ imps,
                              const float* __restrict__ room,
                              float* __restrict__ dry, float* __restrict__ imp) {
  int b = blockIdx.y;
  int n = blockIdx.x * 256 + threadIdx.x;
  float acc = 0.f;
#pragma unroll 4
  for (int j = 0; j < 16; ++j) {
    float v = vals[b * 16 + j];
    int tp = tps[b * 16 + j];
    int ch = chs[b * 16 + j];
    if (v != 0.f && n >= tp)
      acc += v * atoms[(size_t)ch * NSMP + (n - tp)];
  }
  dry[b * NSMP + n] = acc;
  float ia = 0.f;
#pragma unroll
  for (int r = 0; r < 8; ++r)
    ia += room[b * 8 + r] * imps[r * NSMP + n];
  imp[b * NSMP + n] = ia;
}

// ---------------- wet partials (no atomics) ----------------
#define IS(a) is[(a) + ((a) >> 5)]
__global__ __launch_bounds__(256) void wet_kernel(const float* __restrict__ dry,
                                                  const float* __restrict__ impulse,
                                                  float* __restrict__ wp) {
  int s = blockIdx.x;
  int nt = blockIdx.y;
  int b = blockIdx.z;
  if (s > nt) return;
  __shared__ float is[4224];
  __shared__ float dsr[2048];
  int tid = threadIdx.x;
  int n0 = nt * 2048;
  int m0 = s * 2048;
  int base = n0 - m0 - 2047;
  const float* impb = impulse + b * NSMP;
  for (int k = tid; k < 4096; k += 256) {
    int idx = base + k;
    IS(k) = (idx >= 0 && idx < NSMP) ? impb[idx] : 0.f;
  }
  for (int i = tid; i < 2048; i += 256)
    dsr[i] = dry[b * NSMP + m0 + 2047 - i];
  __syncthreads();
  int aw = tid * 8;
  float w[8];
#pragma unroll
  for (int j = 0; j < 8; ++j) w[j] = IS(aw + j);
  float acc[8] = {};
  for (int jb = 0; jb < 2048; jb += 8) {
    float4 d0 = *(const float4*)&dsr[jb];
    float4 d1 = *(const float4*)&dsr[jb + 4];
    float dv[8] = {d0.x, d0.y, d0.z, d0.w, d1.x, d1.y, d1.z, d1.w};
#pragma unroll
    for (int e = 0; e < 8; ++e) {
      float dval = dv[e];
#pragma unroll
      for (int i = 0; i < 8; ++i)
        acc[i] += dval * w[(e + i) & 7];
      w[e] = IS(aw + jb + e + 8);
    }
  }
  float* dst = wp + (size_t)s * (NB * NSMP) + (size_t)b * NSMP + n0 + aw;
  *(float4*)dst = (float4){acc[0], acc[1], acc[2], acc[3]};
  *(float4*)(dst + 4) = (float4){acc[4], acc[5], acc[6], acc[7]};
}

// ---------------- out = dry*mix + (sum_s wp[s])*(1-mix) ----------------
__global__ void out_kernel(const float* __restrict__ dry, const float* __restrict__ wp,
                           const float* __restrict__ mixv, float* __restrict__ out) {
  int b = blockIdx.y;
  int n = blockIdx.x * 256 + threadIdx.x;
  float m = mixv[b];
  float wv = 0.f;
  int smax = n >> 11;
  for (int s = 0; s <= smax; ++s)
    wv += wp[(size_t)s * (NB * NSMP) + b * NSMP + n];
  out[b * NSMP + n] = dry[b * NSMP + n] * m + wv * (1.f - m);
}

extern "C" void kernel_launch(void* const* d_in, const int* in_sizes, int n_in,
                              void* d_out, int out_size, void* d_ws, size_t ws_size,
                              hipStream_t stream) {
  const float* x    = (const float*)d_in[0];
  const float* atoms= (const float*)d_in[1];
  const float* encw = (const float*)d_in[2];
  const float* encb = (const float*)d_in[3];
  const float* upw  = (const float*)d_in[4];
  const float* upb  = (const float*)d_in[5];
  const float* latw = (const float*)d_in[6];
  const float* latb = (const float*)d_in[7];
  const float* rw   = (const float*)d_in[8];
  const float* rb   = (const float*)d_in[9];
  const float* rg   = (const float*)d_in[10];
  const float* rbe  = (const float*)d_in[11];
  const float* rowt = (const float*)d_in[12];
  const float* rob  = (const float*)d_in[13];
  const float* mw   = (const float*)d_in[14];
  const float* mb   = (const float*)d_in[15];
  const float* mg   = (const float*)d_in[16];
  const float* mbe  = (const float*)d_in[17];
  const float* mow  = (const float*)d_in[18];
  const float* mob  = (const float*)d_in[19];
  const float* imps = (const float*)d_in[20];

  float* f    = (float*)d_ws;
  float* h0   = f;                 // 524288
  float* h1   = f + 524288;        // 524288
  float* yp   = f + 1048576;       // 8 x 524288 (conv split-K partials)
  float* ep   = yp;                // 16 x 131072 enc partials alias (post-conv)
  float* wp   = yp + 524288;       // 16 x 131072 wet partials alias (post-topk)
  float* dry  = f + 5242880;       // 131072
  float* imp  = f + 5373952;       // 131072
  float* encf = f + 5505024;       // 131072 (summed enc)
  float* room = f + 5636096;       // 32
  float* mixv = f + 5636128;       // 4
  float* vals = f + 5636160;       // 64
  int*   chs  = (int*)(f + 5636224);
  int*   tps  = (int*)(f + 5636288);
  float* zbuf = f + 5636352;       // 4096 (channel means)
  // bf16 regions
  ushort* w0h  = (ushort*)(f + 6000000);   // 8 x 1024 x 1024 each
  ushort* w0l  = w0h + 8388608;
  ushort* w1h  = w0l + 8388608;
  ushort* w1l  = w1h + 8388608;
  ushort* hTh0 = w1l + 8388608;            // [4][192][1024]
  ushort* hTl0 = hTh0 + 786432;
  ushort* hTh1 = hTl0 + 786432;
  ushort* hTl1 = hTh1 + 786432;

  wsplit_kernel<<<16384, 256, 0, stream>>>(encw, w0h, w0l, w1h, w1l);
  stft_kernel<<<512, 256, 0, stream>>>(x, h0, hTh0, hTl0, hTh1, hTl1);

  float* bufs[2] = {h0, h1};
  ushort* hThb[2] = {hTh0, hTh1};
  ushort* hTlb[2] = {hTl0, hTl1};
  const int dil[8] = {1, 2, 4, 8, 16, 32, 64, 1};
  for (int l = 0; l < 8; ++l) {
    int pi = l & 1, po = (l + 1) & 1;
    conv_mfma<<<dim3(8, 4, 8), 256, 0, stream>>>(
        hThb[pi], hTlb[pi],
        w0h + (size_t)l * 1048576, w0l + (size_t)l * 1048576,
        w1h + (size_t)l * 1048576, w1l + (size_t)l * 1048576,
        dil[l], yp);
    conv_epi<<<dim3(64, 4), 256, 0, stream>>>(yp, bufs[pi], encb + l * 1024,
                                              bufs[po], hThb[po], hTlb[po], zbuf);
  }
  // final h in h0; zbuf holds layer-7 channel means

  dense_mlp_kernel<<<4, 64, 0, stream>>>(zbuf, latw, latb, rw, rb, rg, rbe, rowt, rob,
                                         mw, mb, mg, mbe, mow, mob, room, mixv);
  gemm_f32<1, 0, 1024, 16, 256><<<dim3(4, 4, 16), 256, 0, stream>>>(h0, upw, ep);
  encsum_kernel<<<dim3(32, 4), 256, 0, stream>>>(ep, upb, encf);
  topk_kernel<<<4, 256, 0, stream>>>(encf, vals, chs, tps);
  dryimp_kernel<<<dim3(128, 4), 256, 0, stream>>>(atoms, vals, chs, tps, imps, room, dry, imp);
  wet_kernel<<<dim3(16, 16, 4), 256, 0, stream>>>(dry, imp, wp);
  out_kernel<<<dim3(128, 4), 256, 0, stream>>>(dry, wp, mixv, (float*)d_out);
}

// Round 14
// 486.045 us; speedup vs baseline: 2.0809x; 1.1585x over previous
//
#include <hip/hip_runtime.h>
#include <hip/hip_bf16.h>
#include <math.h>

#define NSMP 32768
#define NFR 128
#define NCH 1024
#define NB 4

typedef __attribute__((ext_vector_type(8))) short short8;
typedef __attribute__((ext_vector_type(4))) float f32x4;
typedef unsigned short ushort;

__device__ __forceinline__ void split_bf(float v, ushort& h, ushort& l) {
  __hip_bfloat16 bh = __float2bfloat16(v);
  float r = v - __bfloat162float(bh);
  __hip_bfloat16 bl = __float2bfloat16(r);
  h = *reinterpret_cast<ushort*>(&bh);
  l = *reinterpret_cast<ushort*>(&bl);
}

__device__ __forceinline__ void gload_lds16(const ushort* g, ushort* l) {
  __builtin_amdgcn_global_load_lds((const __attribute__((address_space(1))) void*)g,
                                   (__attribute__((address_space(3))) void*)l, 16, 0, 0);
}

// ---------------- STFT: emits h (f32) + transposed hi/lo bf16 hT[t][c]; zeros hT pad rows ----------------
__global__ __launch_bounds__(256) void stft_kernel(const float* __restrict__ x,
                                                   float* __restrict__ h,
                                                   ushort* __restrict__ hTh,
                                                   ushort* __restrict__ hTl,
                                                   ushort* __restrict__ hTh1,
                                                   ushort* __restrict__ hTl1) {
  __shared__ float re[2048];
  __shared__ float im[2048];
  __shared__ float twr[1024];
  __shared__ float twi[1024];
  int bid = blockIdx.x;
  int b = bid >> 7;
  int f = bid & 127;
  int tid = threadIdx.x;
  const float TWO_PI = 6.28318530717958647692f;
  if (f < 64) {
    size_t pidx = ((size_t)b * 192 + 128 + f) * 1024 + tid * 4;
    uint2 z = {0u, 0u};
    *(uint2*)&hTh[pidx] = z;  *(uint2*)&hTl[pidx] = z;
    *(uint2*)&hTh1[pidx] = z; *(uint2*)&hTl1[pidx] = z;
  }
  for (int k = tid; k < 1024; k += 256) {
    float ang = -TWO_PI * (float)k / 2048.0f;
    float sn, cs;
    sincosf(ang, &sn, &cs);
    twr[k] = cs; twi[k] = sn;
  }
  for (int i = tid; i < 2048; i += 256) {
    int rev = (int)(__brev((unsigned)i) >> 21);
    int pos = f * 256 + rev;
    float v = (pos < NSMP) ? x[b * NSMP + pos] : 0.f;
    float w = 0.5f - 0.5f * cosf(TWO_PI * (float)rev / 2047.0f);  // jnp.hanning(2048)
    re[i] = v * w;
    im[i] = 0.f;
  }
  __syncthreads();
  for (int s = 0; s < 11; ++s) {
    for (int q = 0; q < 4; ++q) {
      int bi = tid + q * 256;
      int half = 1 << s;
      int j = bi & (half - 1);
      int i0 = ((bi >> s) << (s + 1)) | j;
      int i1 = i0 + half;
      int ti = j << (10 - s);
      float cs = twr[ti], sn = twi[ti];
      float ur = re[i0], ui = im[i0];
      float vr = re[i1], vi = im[i1];
      float tr = vr * cs - vi * sn;
      float tti = vr * sn + vi * cs;
      re[i0] = ur + tr; im[i0] = ui + tti;
      re[i1] = ur - tr; im[i1] = ui - tti;
    }
    __syncthreads();
  }
  for (int k = tid; k < 1024; k += 256) {
    float m = sqrtf(re[k] * re[k] + im[k] * im[k]);
    h[(b * NCH + k) * NFR + f] = m;
    ushort hi, lo;
    split_bf(m, hi, lo);
    size_t tidx = ((size_t)b * 192 + f) * 1024 + k;
    hTh[tidx] = hi;
    hTl[tidx] = lo;
  }
}

// ---------------- split encw into per-tap hi/lo bf16 weight arrays ----------------
__global__ __launch_bounds__(256) void wsplit_kernel(const float* __restrict__ encw,
                                                     ushort* __restrict__ w0h, ushort* __restrict__ w0l,
                                                     ushort* __restrict__ w1h, ushort* __restrict__ w1l) {
  size_t F = (size_t)blockIdx.x * 256 + threadIdx.x;  // 4,194,304 float4s
  float4 v = ((const float4*)encw)[F];
  size_t lo_idx = F >> 9;            // l*1024+o
  int c0 = (int)(F & 511) * 2;
  size_t base = lo_idx * 1024 + c0;
  ushort h0, l0, h1, l1;
  split_bf(v.x, h0, l0);
  split_bf(v.z, h1, l1);
  *(ushort2*)&w0h[base] = (ushort2){h0, h1};
  *(ushort2*)&w0l[base] = (ushort2){l0, l1};
  split_bf(v.y, h0, l0);
  split_bf(v.w, h1, l1);
  *(ushort2*)&w1h[base] = (ushort2){h0, h1};
  *(ushort2*)&w1l[base] = (ushort2){l0, l1};
}

// ---------------- conv GEMM: split-bf16 3-product MFMA, counted-vmcnt triple-buffer (round-10 version) ----------------
__global__ __launch_bounds__(256) void conv_mfma(const ushort* __restrict__ hTh,
                                                 const ushort* __restrict__ hTl,
                                                 const ushort* __restrict__ w0h, const ushort* __restrict__ w0l,
                                                 const ushort* __restrict__ w1h, const ushort* __restrict__ w1l,
                                                 int D, float* __restrict__ yp) {
  __shared__ ushort lds[49152];  // 3 buffers x 16384 ushorts
  int tid = threadIdx.x;
  int og = blockIdx.x * 128;
  int b = blockIdx.y;
  int s = blockIdx.z;
  int wid = tid >> 6, lane = tid & 63;
  int wr = (wid >> 1) * 64, wc = (wid & 1) * 64;
  int lr = lane & 15, lk = lane >> 4;
  int srow = lane >> 2;
  int sgr = ((lane & 3) ^ ((lane >> 3) & 3)) * 8;

  f32x4 acc[4][4];
#pragma unroll
  for (int m = 0; m < 4; ++m)
#pragma unroll
    for (int n = 0; n < 4; ++n) acc[m][n] = (f32x4){0.f, 0.f, 0.f, 0.f};

  const ushort* hb_h = hTh + (size_t)b * 192 * 1024;
  const ushort* hb_l = hTl + (size_t)b * 192 * 1024;

  auto stage = [&](int buf, int p) {
    const ushort* Wh = (p < 4) ? w0h : w1h;
    const ushort* Wl = (p < 4) ? w0l : w1l;
    int rowoff = (p < 4) ? 0 : D;
    int c0 = s * 128 + (p & 3) * 32 + sgr;
    ushort* dbase = &lds[buf * 16384 + wid * 4096];
#pragma unroll
    for (int j = 0; j < 8; ++j) {
      int row = j * 16 + srow;
      const ushort* src;
      if (wid == 0)      src = Wh   + (size_t)(og + row) * 1024 + c0;
      else if (wid == 1) src = Wl   + (size_t)(og + row) * 1024 + c0;
      else if (wid == 2) src = hb_h + (size_t)(rowoff + row) * 1024 + c0;
      else               src = hb_l + (size_t)(rowoff + row) * 1024 + c0;
      gload_lds16(src, dbase + j * 512);
    }
  };

  auto compute = [&](int buf) {
    const ushort* base = &lds[buf * 16384];
    short8 ah[4], al[4], bh[4], bl[4];
#pragma unroll
    for (int m = 0; m < 4; ++m) {
      int ar = wr + m * 16 + lr;
      int off = ar * 32 + ((lk ^ ((ar >> 1) & 3)) << 3);
      ah[m] = *(const short8*)&base[off];
      al[m] = *(const short8*)&base[4096 + off];
    }
#pragma unroll
    for (int n = 0; n < 4; ++n) {
      int br = wc + n * 16 + lr;
      int off = br * 32 + ((lk ^ ((br >> 1) & 3)) << 3);
      bh[n] = *(const short8*)&base[8192 + off];
      bl[n] = *(const short8*)&base[12288 + off];
    }
#pragma unroll
    for (int m = 0; m < 4; ++m)
#pragma unroll
      for (int n = 0; n < 4; ++n) {
        acc[m][n] = __builtin_amdgcn_mfma_f32_16x16x32_bf16(ah[m], bh[n], acc[m][n], 0, 0, 0);
        acc[m][n] = __builtin_amdgcn_mfma_f32_16x16x32_bf16(ah[m], bl[n], acc[m][n], 0, 0, 0);
        acc[m][n] = __builtin_amdgcn_mfma_f32_16x16x32_bf16(al[m], bh[n], acc[m][n], 0, 0, 0);
      }
  };

  stage(0, 0);
  stage(1, 1);
#pragma unroll
  for (int p = 0; p < 8; ++p) {
    if (p < 7) asm volatile("s_waitcnt vmcnt(8)" ::: "memory");
    else       asm volatile("s_waitcnt vmcnt(0)" ::: "memory");
    __builtin_amdgcn_s_barrier();
    if (p + 2 < 8) stage((p + 2) % 3, p + 2);
    compute(p % 3);
  }

  float* dst = yp + (size_t)(s * 4 + b) * 131072;
#pragma unroll
  for (int m = 0; m < 4; ++m)
#pragma unroll
    for (int n = 0; n < 4; ++n)
#pragma unroll
      for (int r = 0; r < 4; ++r) {
        int orow = og + wr + m * 16 + lk * 4 + r;
        int col = wc + n * 16 + lr;
        dst[orow * 128 + col] = acc[m][n][r];
      }
}

// ---------------- conv epilogue: residual+bias+lrelu, emit f32 h + hi/lo hT + channel-mean z ----------------
__global__ __launch_bounds__(256) void conv_epi(const float* __restrict__ yp,
                                                const float* __restrict__ hin,
                                                const float* __restrict__ bias,
                                                float* __restrict__ hout,
                                                ushort* __restrict__ hTh,
                                                ushort* __restrict__ hTl,
                                                float* __restrict__ zbuf) {
  __shared__ float T[16][132];
  int og = blockIdx.x * 16;
  int b = blockIdx.y;
  int tid = threadIdx.x;
#pragma unroll
  for (int j = 0; j < 8; ++j) {
    int flat = j * 256 + tid;          // 2048 = 16 o x 128 t
    int o = flat >> 7, t = flat & 127;
    size_t base = ((size_t)b * NCH + og + o) * NFR + t;
    float v = 0.f;
#pragma unroll
    for (int sl = 0; sl < 8; ++sl) v += yp[(size_t)sl * 524288 + base];
    v += bias[og + o];
    v = (v > 0.f) ? v : 0.2f * v;
    float r = hin[base] + v;
    hout[base] = r;
    T[o][t] = r;
  }
  __syncthreads();
  if (tid < 16) {   // z[b][c] = mean_t h  (layer 7's write is the one consumed)
    float sm = 0.f;
#pragma unroll 8
    for (int t = 0; t < 128; ++t) sm += T[tid][t];
    zbuf[b * NCH + og + tid] = sm * (1.f / 128.f);
  }
#pragma unroll
  for (int j = 0; j < 8; ++j) {
    int flat = j * 256 + tid;
    int t = flat >> 4, o = flat & 15;
    ushort hi, lo;
    split_bf(T[o][t], hi, lo);
    size_t tidx = ((size_t)b * 192 + t) * 1024 + og + o;
    hTh[tidx] = hi;
    hTl[tidx] = lo;
  }
}

// ---------------- f32 GEMM (enc only), K-split partials ----------------
template <int TAPS, int D, int KTOT, int SPLIT, int MROWS>
__global__ __launch_bounds__(256, 2) void gemm_f32(const float* __restrict__ hin,
                                                   const float* __restrict__ W,
                                                   float* __restrict__ yp) {
  __shared__ float As[64][68];
  __shared__ float Bs[64][132];
  int tid = threadIdx.x;
  int og = blockIdx.x * 64;
  int b = blockIdx.y;
  int s = blockIdx.z;
  const float* hb = hin + (size_t)b * (NCH * NFR);
  int tx = tid & 15;
  int ty = tid >> 4;
  float acc[4][8] = {};
  const int KS = KTOT / SPLIT;
  for (int kt = 0; kt < KS / 64; ++kt) {
    int k0 = s * KS + kt * 64;
    __syncthreads();
    {
      int r = tid >> 2;
      int seg = (tid & 3) * 16;
      const float4* src = (const float4*)(W + (size_t)(og + r) * KTOT + k0 + seg);
#pragma unroll
      for (int q = 0; q < 4; ++q) {
        float4 v = src[q];
        int row = seg + 4 * q;
#pragma unroll
        for (int i = 0; i < 4; ++i) {
          int rr = row + i;
          int col = r ^ (((rr >> 4) & 1) << 2);
          float val = (i == 0) ? v.x : (i == 1) ? v.y : (i == 2) ? v.z : v.w;
          As[rr][col] = val;
        }
      }
    }
    {
      int r = tid >> 2;
      int tq = (tid & 3) * 32;
      int c = k0 + r;
      const float4* src = (const float4*)(hb + (size_t)c * NFR + tq);
#pragma unroll
      for (int q = 0; q < 8; ++q) *(float4*)&Bs[r][tq + 4 * q] = src[q];
    }
    __syncthreads();
#pragma unroll 8
    for (int kk = 0; kk < 64; ++kk) {
      int ca = (ty * 4) ^ (((kk >> 4) & 1) << 2);
      float4 a0 = *(const float4*)&As[kk][ca];
      float4 b0 = *(const float4*)&Bs[kk][tx * 4];
      float4 b1 = *(const float4*)&Bs[kk][tx * 4 + 64];
      float av[4] = {a0.x, a0.y, a0.z, a0.w};
      float bv[8] = {b0.x, b0.y, b0.z, b0.w, b1.x, b1.y, b1.z, b1.w};
#pragma unroll
      for (int i = 0; i < 4; ++i)
#pragma unroll
        for (int j = 0; j < 8; ++j)
          acc[i][j] += av[i] * bv[j];
    }
  }
  float* ypb = yp + (size_t)s * (NB * MROWS * NFR) + (size_t)b * MROWS * NFR;
#pragma unroll
  for (int i = 0; i < 4; ++i) {
    int o = og + ty * 4 + i;
    *(float4*)&ypb[o * NFR + tx * 4] = (float4){acc[i][0], acc[i][1], acc[i][2], acc[i][3]};
    *(float4*)&ypb[o * NFR + tx * 4 + 64] = (float4){acc[i][4], acc[i][5], acc[i][6], acc[i][7]};
  }
}

// ---------------- fused tail: blocks x<32 = enc partial-sum; block x==32 = MLP heads ----------------
__global__ __launch_bounds__(256) void tail_kernel(
    const float* __restrict__ ep, const float* __restrict__ upb, float* __restrict__ enc,
    const float* __restrict__ zbuf,
    const float* __restrict__ latw, const float* __restrict__ latb,
    const float* __restrict__ rw, const float* __restrict__ rb,
    const float* __restrict__ rg, const float* __restrict__ rbe,
    const float* __restrict__ rowt, const float* __restrict__ rob,
    const float* __restrict__ mw, const float* __restrict__ mb,
    const float* __restrict__ mg, const float* __restrict__ mbe,
    const float* __restrict__ mow, const float* __restrict__ mob,
    float* __restrict__ room, float* __restrict__ mixv) {
  int b = blockIdx.y;
  int tid = threadIdx.x;
  if (blockIdx.x < 32) {
    // ---- encsum: enc = sum_16 ep + bias ----
    int i4 = blockIdx.x * 256 + tid;   // float4 index within batch (8192)
    int i = i4 * 4;
    float bv = upb[i >> 7];
    float4 s = {bv, bv, bv, bv};
#pragma unroll
    for (int sl = 0; sl < 16; ++sl) {
      float4 p = *(const float4*)&ep[(size_t)sl * 131072 + b * 32768 + i];
      s.x += p.x; s.y += p.y; s.z += p.z; s.w += p.w;
    }
    *(float4*)&enc[b * 32768 + i] = s;
    return;
  }
  // ---- MLP heads (z precomputed), one wave ----
  if (tid >= 64) return;
  const float* z = zbuf + b * NCH;
  int j = tid & 15;
  int p = tid >> 4;
  float dsum = 0.f;
  for (int c = p * 256; c < p * 256 + 256; ++c)
    dsum += z[c] * latw[c * 16 + j];
  dsum += __shfl_xor(dsum, 16);
  dsum += __shfl_xor(dsum, 32);
  float dj = dsum + latb[j];
  float sq = dj * dj;
  sq += __shfl_xor(sq, 1, 16);
  sq += __shfl_xor(sq, 2, 16);
  sq += __shfl_xor(sq, 4, 16);
  sq += __shfl_xor(sq, 8, 16);
  float a = dj / (sqrtf(sq) + 1e-8f);

  const float* W = rw;  const float* Bb = rb;
  const float* G = rg;  const float* Be = rbe;
  for (int which = 0; which < 2; ++which) {
    float v = a;
    for (int l = 0; l < 3; ++l) {
      float accv = Bb[l * 16 + j];
      for (int k = 0; k < 16; ++k) {
        float ak = __shfl(v, (tid & 48) | k);
        accv += ak * W[(l * 16 + k) * 16 + j];
      }
      float mu = accv;
      mu += __shfl_xor(mu, 1, 16); mu += __shfl_xor(mu, 2, 16);
      mu += __shfl_xor(mu, 4, 16); mu += __shfl_xor(mu, 8, 16);
      mu *= (1.f / 16.f);
      float dv = accv - mu;
      float var = dv * dv;
      var += __shfl_xor(var, 1, 16); var += __shfl_xor(var, 2, 16);
      var += __shfl_xor(var, 4, 16); var += __shfl_xor(var, 8, 16);
      var *= (1.f / 16.f);
      float xn = dv * rsqrtf(var + 1e-5f) * G[l * 16 + j] + Be[l * 16 + j];
      v = (xn > 0.f) ? xn : 0.2f * xn;
    }
    if (which == 0) {
      int r = tid & 7;
      float logit = rob[r];
      for (int k = 0; k < 16; ++k) {
        float ak = __shfl(v, (tid & 48) | k);
        logit += ak * rowt[k * 8 + r];
      }
      float mx = logit;
      mx = fmaxf(mx, __shfl_xor(mx, 1, 8));
      mx = fmaxf(mx, __shfl_xor(mx, 2, 8));
      mx = fmaxf(mx, __shfl_xor(mx, 4, 8));
      float e = expf(logit - mx);
      float se = e;
      se += __shfl_xor(se, 1, 8);
      se += __shfl_xor(se, 2, 8);
      se += __shfl_xor(se, 4, 8);
      if (tid < 8) room[b * 8 + r] = e / se;
      W = mw; Bb = mb; G = mg; Be = mbe;
    } else {
      float logit = mob[0];
      for (int k = 0; k < 16; ++k) {
        float ak = __shfl(v, (tid & 48) | k);
        logit += ak * mow[k];
      }
      if (tid == 0) mixv[b] = 1.f / (1.f + expf(-logit));
    }
  }
}

// ---------------- top-16 (jax tie semantics) over pre-summed enc ----------------
__global__ __launch_bounds__(256) void topk_kernel(const float* __restrict__ enc,
                                                   float* __restrict__ vals,
                                                   int* __restrict__ chs,
                                                   int* __restrict__ tps) {
  __shared__ float swv[4];
  __shared__ int swi[4];
  int b = blockIdx.x;
  int tid = threadIdx.x;
  const float* e = enc + b * 32768;
  float lv[16];
  int li[16];
#pragma unroll
  for (int q = 0; q < 16; ++q) { lv[q] = -INFINITY; li[q] = 0x7fffffff; }
  for (int i = tid; i < 32768; i += 256) {
    float v = e[i];
    if (v > lv[15]) {
      float cv = v; int ci = i;
#pragma unroll
      for (int q = 0; q < 16; ++q) {
        if (cv > lv[q]) {
          float tv = lv[q]; int ti = li[q];
          lv[q] = cv; li[q] = ci;
          cv = tv; ci = ti;
        }
      }
    }
  }
  for (int round = 0; round < 16; ++round) {
    float cv = lv[0];
    int ci = li[0];
#pragma unroll
    for (int off = 1; off < 64; off <<= 1) {
      float ov = __shfl_xor(cv, off);
      int oi = __shfl_xor(ci, off);
      if (ov > cv || (ov == cv && oi < ci)) { cv = ov; ci = oi; }
    }
    if ((tid & 63) == 0) { swv[tid >> 6] = cv; swi[tid >> 6] = ci; }
    __syncthreads();
    float wv = swv[0]; int wi = swi[0];
#pragma unroll
    for (int w = 1; w < 4; ++w) {
      float v2 = swv[w]; int i2 = swi[w];
      if (v2 > wv || (v2 == wv && i2 < wi)) { wv = v2; wi = i2; }
    }
    if (tid == 0) {
      vals[b * 16 + round] = (wv > 0.f) ? wv : 0.f;
      chs[b * 16 + round] = wi >> 7;
      tps[b * 16 + round] = (wi & 127) * 256;
    }
    if (li[0] == wi) {
#pragma unroll
      for (int q = 0; q < 15; ++q) { lv[q] = lv[q + 1]; li[q] = li[q + 1]; }
      lv[15] = -INFINITY; li[15] = 0x7fffffff;
    }
    __syncthreads();
  }
}

// ---------------- dry + impulse fused ----------------
__global__ void dryimp_kernel(const float* __restrict__ atoms,
                              const float* __restrict__ vals, const int* __restrict__ chs,
                              const int* __restrict__ tps, const float* __restrict__ imps,
                              const float* __restrict__ room,
                              float* __restrict__ dry, float* __restrict__ imp) {
  int b = blockIdx.y;
  int n = blockIdx.x * 256 + threadIdx.x;
  float acc = 0.f;
#pragma unroll 4
  for (int j = 0; j < 16; ++j) {
    float v = vals[b * 16 + j];
    int tp = tps[b * 16 + j];
    int ch = chs[b * 16 + j];
    if (v != 0.f && n >= tp)
      acc += v * atoms[(size_t)ch * NSMP + (n - tp)];
  }
  dry[b * NSMP + n] = acc;
  float ia = 0.f;
#pragma unroll
  for (int r = 0; r < 8; ++r)
    ia += room[b * 8 + r] * imps[r * NSMP + n];
  imp[b * NSMP + n] = ia;
}

// ---------------- wet partials (no atomics) ----------------
#define IS(a) is[(a) + ((a) >> 5)]
__global__ __launch_bounds__(256) void wet_kernel(const float* __restrict__ dry,
                                                  const float* __restrict__ impulse,
                                                  float* __restrict__ wp) {
  int s = blockIdx.x;
  int nt = blockIdx.y;
  int b = blockIdx.z;
  if (s > nt) return;
  __shared__ float is[4224];
  __shared__ float dsr[2048];
  int tid = threadIdx.x;
  int n0 = nt * 2048;
  int m0 = s * 2048;
  int base = n0 - m0 - 2047;
  const float* impb = impulse + b * NSMP;
  for (int k = tid; k < 4096; k += 256) {
    int idx = base + k;
    IS(k) = (idx >= 0 && idx < NSMP) ? impb[idx] : 0.f;
  }
  for (int i = tid; i < 2048; i += 256)
    dsr[i] = dry[b * NSMP + m0 + 2047 - i];
  __syncthreads();
  int aw = tid * 8;
  float w[8];
#pragma unroll
  for (int j = 0; j < 8; ++j) w[j] = IS(aw + j);
  float acc[8] = {};
  for (int jb = 0; jb < 2048; jb += 8) {
    float4 d0 = *(const float4*)&dsr[jb];
    float4 d1 = *(const float4*)&dsr[jb + 4];
    float dv[8] = {d0.x, d0.y, d0.z, d0.w, d1.x, d1.y, d1.z, d1.w};
#pragma unroll
    for (int e = 0; e < 8; ++e) {
      float dval = dv[e];
#pragma unroll
      for (int i = 0; i < 8; ++i)
        acc[i] += dval * w[(e + i) & 7];
      w[e] = IS(aw + jb + e + 8);
    }
  }
  float* dst = wp + (size_t)s * (NB * NSMP) + (size_t)b * NSMP + n0 + aw;
  *(float4*)dst = (float4){acc[0], acc[1], acc[2], acc[3]};
  *(float4*)(dst + 4) = (float4){acc[4], acc[5], acc[6], acc[7]};
}

// ---------------- out = dry*mix + (sum_s wp[s])*(1-mix) ----------------
__global__ void out_kernel(const float* __restrict__ dry, const float* __restrict__ wp,
                           const float* __restrict__ mixv, float* __restrict__ out) {
  int b = blockIdx.y;
  int n = blockIdx.x * 256 + threadIdx.x;
  float m = mixv[b];
  float wv = 0.f;
  int smax = n >> 11;
  for (int s = 0; s <= smax; ++s)
    wv += wp[(size_t)s * (NB * NSMP) + b * NSMP + n];
  out[b * NSMP + n] = dry[b * NSMP + n] * m + wv * (1.f - m);
}

extern "C" void kernel_launch(void* const* d_in, const int* in_sizes, int n_in,
                              void* d_out, int out_size, void* d_ws, size_t ws_size,
                              hipStream_t stream) {
  const float* x    = (const float*)d_in[0];
  const float* atoms= (const float*)d_in[1];
  const float* encw = (const float*)d_in[2];
  const float* encb = (const float*)d_in[3];
  const float* upw  = (const float*)d_in[4];
  const float* upb  = (const float*)d_in[5];
  const float* latw = (const float*)d_in[6];
  const float* latb = (const float*)d_in[7];
  const float* rw   = (const float*)d_in[8];
  const float* rb   = (const float*)d_in[9];
  const float* rg   = (const float*)d_in[10];
  const float* rbe  = (const float*)d_in[11];
  const float* rowt = (const float*)d_in[12];
  const float* rob  = (const float*)d_in[13];
  const float* mw   = (const float*)d_in[14];
  const float* mb   = (const float*)d_in[15];
  const float* mg   = (const float*)d_in[16];
  const float* mbe  = (const float*)d_in[17];
  const float* mow  = (const float*)d_in[18];
  const float* mob  = (const float*)d_in[19];
  const float* imps = (const float*)d_in[20];

  float* f    = (float*)d_ws;
  float* h0   = f;                 // 524288
  float* h1   = f + 524288;        // 524288
  float* yp   = f + 1048576;       // 8 x 524288 (conv split-K partials)
  float* ep   = yp;                // 16 x 131072 enc partials alias (post-conv)
  float* wp   = yp + 524288;       // 16 x 131072 wet partials alias (post-topk)
  float* dry  = f + 5242880;       // 131072
  float* imp  = f + 5373952;       // 131072
  float* encf = f + 5505024;       // 131072 (summed enc)
  float* room = f + 5636096;       // 32
  float* mixv = f + 5636128;       // 4
  float* vals = f + 5636160;       // 64
  int*   chs  = (int*)(f + 5636224);
  int*   tps  = (int*)(f + 5636288);
  float* zbuf = f + 5636352;       // 4096 (channel means)
  // bf16 regions
  ushort* w0h  = (ushort*)(f + 6000000);   // 8 x 1024 x 1024 each
  ushort* w0l  = w0h + 8388608;
  ushort* w1h  = w0l + 8388608;
  ushort* w1l  = w1h + 8388608;
  ushort* hTh0 = w1l + 8388608;            // [4][192][1024]
  ushort* hTl0 = hTh0 + 786432;
  ushort* hTh1 = hTl0 + 786432;
  ushort* hTl1 = hTh1 + 786432;

  wsplit_kernel<<<16384, 256, 0, stream>>>(encw, w0h, w0l, w1h, w1l);
  stft_kernel<<<512, 256, 0, stream>>>(x, h0, hTh0, hTl0, hTh1, hTl1);

  float* bufs[2] = {h0, h1};
  ushort* hThb[2] = {hTh0, hTh1};
  ushort* hTlb[2] = {hTl0, hTl1};
  const int dil[8] = {1, 2, 4, 8, 16, 32, 64, 1};
  for (int l = 0; l < 8; ++l) {
    int pi = l & 1, po = (l + 1) & 1;
    conv_mfma<<<dim3(8, 4, 8), 256, 0, stream>>>(
        hThb[pi], hTlb[pi],
        w0h + (size_t)l * 1048576, w0l + (size_t)l * 1048576,
        w1h + (size_t)l * 1048576, w1l + (size_t)l * 1048576,
        dil[l], yp);
    conv_epi<<<dim3(64, 4), 256, 0, stream>>>(yp, bufs[pi], encb + l * 1024,
                                              bufs[po], hThb[po], hTlb[po], zbuf);
  }
  // final h in h0; zbuf holds layer-7 channel means

  gemm_f32<1, 0, 1024, 16, 256><<<dim3(4, 4, 16), 256, 0, stream>>>(h0, upw, ep);
  tail_kernel<<<dim3(33, 4), 256, 0, stream>>>(ep, upb, encf, zbuf,
                                               latw, latb, rw, rb, rg, rbe, rowt, rob,
                                               mw, mb, mg, mbe, mow, mob, room, mixv);
  topk_kernel<<<4, 256, 0, stream>>>(encf, vals, chs, tps);
  dryimp_kernel<<<dim3(128, 4), 256, 0, stream>>>(atoms, vals, chs, tps, imps, room, dry, imp);
  wet_kernel<<<dim3(16, 16, 4), 256, 0, stream>>>(dry, imp, wp);
  out_kernel<<<dim3(128, 4), 256, 0, stream>>>(dry, wp, mixv, (float*)d_out);
}